// Round 3
// baseline (660.415 us; speedup 1.0000x reference)
//
#include <hip/hip_runtime.h>
#include <hip/hip_bf16.h>
#include <cstdint>
#include <cstddef>

#define TT 2048
#define HH 1024
#define FF 2816
#define EE 8
#define BK 64
#define NROWS (TT * 2)   // total expert-assignment rows (top_k = 2)

typedef short bf16x8 __attribute__((ext_vector_type(8)));   // 8 bf16 = 4 VGPRs
typedef float f32x4v __attribute__((ext_vector_type(4)));
typedef float vf4    __attribute__((ext_vector_type(4)));
typedef unsigned int uint32;

__device__ __forceinline__ unsigned short f2bf(float f) {
    union { float f; uint32 u; } v; v.f = f;
    uint32 u = v.u;
    uint32 r = (u + 0x7FFFu + ((u >> 16) & 1u)) >> 16;  // RNE
    return (unsigned short)r;
}

// ---------------- router: logits, softmax-top2, renormalized weights ----------------
__global__ void k_router(const float* __restrict__ x, const float* __restrict__ rw,
                         int* __restrict__ tke, float* __restrict__ tkw,
                         int* __restrict__ counts)
{
    int t = blockIdx.x * 4 + (threadIdx.x >> 6);   // 4 waves per block, 1 token/wave
    int lane = threadIdx.x & 63;
    const float* xr = x + (size_t)t * HH;
    float acc[EE];
#pragma unroll
    for (int e = 0; e < EE; ++e) acc[e] = 0.f;
#pragma unroll
    for (int i = 0; i < HH / 64; ++i) {
        int h = i * 64 + lane;
        float xv = xr[h];
        const vf4* w = (const vf4*)(rw + (size_t)h * EE);
        vf4 w0 = w[0], w1 = w[1];
#pragma unroll
        for (int e = 0; e < 4; ++e) {
            acc[e]     = fmaf(xv, w0[e], acc[e]);
            acc[4 + e] = fmaf(xv, w1[e], acc[4 + e]);
        }
    }
#pragma unroll
    for (int e = 0; e < EE; ++e) {
        float v = acc[e];
#pragma unroll
        for (int m = 1; m < 64; m <<= 1) v += __shfl_xor(v, m, 64);
        acc[e] = v;
    }
    if (lane == 0) {
        int e1 = 0; float l1 = acc[0];
#pragma unroll
        for (int e = 1; e < EE; ++e) if (acc[e] > l1) { l1 = acc[e]; e1 = e; }
        int e2 = (e1 == 0) ? 1 : 0; float l2 = acc[e2];
#pragma unroll
        for (int e = 0; e < EE; ++e) if (e != e1 && acc[e] > l2) { l2 = acc[e]; e2 = e; }
        // softmax + top2 renormalize == 2-way softmax over (l1, l2)
        float w1 = 1.f / (1.f + __expf(l2 - l1));
        float w2 = 1.f - w1;
        tke[t * 2] = e1; tke[t * 2 + 1] = e2;
        tkw[t * 2] = w1; tkw[t * 2 + 1] = w2;
        atomicAdd(&counts[e1], 1);
        atomicAdd(&counts[e2], 1);
    }
}

// ---------------- x fp32 -> bf16 ----------------
__global__ void k_convert_x(const float* __restrict__ x, unsigned short* __restrict__ xb)
{
    int i = (blockIdx.x * 256 + threadIdx.x) * 8;
    vf4 a = *(const vf4*)(x + i);
    vf4 b = *(const vf4*)(x + i + 4);
    uint4 o;
    o.x = (uint32)f2bf(a[0]) | ((uint32)f2bf(a[1]) << 16);
    o.y = (uint32)f2bf(a[2]) | ((uint32)f2bf(a[3]) << 16);
    o.z = (uint32)f2bf(b[0]) | ((uint32)f2bf(b[1]) << 16);
    o.w = (uint32)f2bf(b[2]) | ((uint32)f2bf(b[3]) << 16);
    *(uint4*)(xb + i) = o;
}

// ---------------- segment offsets (prefix sum over 8 experts) ----------------
__global__ void k_offsets(const int* __restrict__ counts, int* __restrict__ offs)
{
    if (threadIdx.x == 0) {
        int s = 0;
#pragma unroll
        for (int e = 0; e < EE; ++e) { offs[e] = s; s += counts[e]; }
        offs[EE] = s;
    }
}

// ---------------- scatter token assignments into per-expert segments ----------------
__global__ void k_scatter(const int* __restrict__ tke, const float* __restrict__ tkw,
                          const int* __restrict__ offs, int* __restrict__ cursor,
                          int* __restrict__ row_tok, int* __restrict__ row_slot,
                          float* __restrict__ row_w)
{
    int t = blockIdx.x * 256 + threadIdx.x;
    if (t >= TT) return;
#pragma unroll
    for (int k = 0; k < 2; ++k) {
        int e = tke[t * 2 + k];
        int pos = atomicAdd(&cursor[e], 1);
        int r = offs[e] + pos;
        row_tok[r] = t;
        row_slot[r] = k;
        row_w[r] = tkw[t * 2 + k];
    }
}

// ---------------- GEMM1: h = silu(x*Wg) * (x*Wu), per expert, gathered rows ----------
// tiles: BM=128, BN=64 (x2 matrices), BK=64; 4 waves (2x2), wave computes 64x32 of g and u
__global__ __launch_bounds__(256, 2)
void k_gemm1(const unsigned short* __restrict__ xb,
             const float* __restrict__ wg, const float* __restrict__ wu,
             const int* __restrict__ offs, const int* __restrict__ row_tok,
             unsigned short* __restrict__ hb)
{
    const int e  = blockIdx.y >> 4;
    const int mt = blockIdx.y & 15;
    const int seg0 = offs[e];
    const int n_e  = offs[e + 1] - seg0;
    const int m0 = mt * 128;
    if (m0 >= n_e) return;
    const int nb = blockIdx.x * 64;

    const float* Wg = wg + (size_t)e * HH * FF;
    const float* Wu = wu + (size_t)e * HH * FF;

    __shared__ __align__(16) unsigned char smem[32768];
    // A: [0,16384)  (128 rows x 128B, XOR-swizzled)
    // Bg:[16384,24576)  Bu:[24576,32768)  (64 n-rows x 128B, transposed, swizzled)

    const int tid  = threadIdx.x;
    const int lane = tid & 63;
    const int wid  = tid >> 6;
    const int wr = wid >> 1, wc = wid & 1;

    // A staging: 4 16B chunks per thread
    int    a_lds[4];
    size_t a_gbl[4];
#pragma unroll
    for (int i = 0; i < 4; ++i) {
        int flat = tid + i * 256;
        int r  = flat >> 3;
        int cb = (flat & 7) * 16;
        int idx = m0 + r;
        int cidx = idx < n_e ? idx : (n_e - 1);
        int tok = row_tok[seg0 + cidx];
        a_gbl[i] = (size_t)tok * (HH * 2) + (size_t)cb;
        a_lds[i] = r * 128 + (cb ^ ((r & 7) << 4));
    }
    // B staging: 4x4 fp32 block -> transpose -> 4 x b64 bf16 writes
    const int gn = tid & 15, gk = tid >> 4;
    const int bn0 = gn * 4, bk0 = gk * 4;
    int b_lds[4];
#pragma unroll
    for (int i = 0; i < 4; ++i) {
        int n = bn0 + i;
        b_lds[i] = n * 128 + ((bk0 * 2) ^ ((n & 7) << 4));
    }

    f32x4v zero4 = {0.f, 0.f, 0.f, 0.f};
    f32x4v accg[4][2], accu[4][2];
#pragma unroll
    for (int mi = 0; mi < 4; ++mi)
#pragma unroll
        for (int ni = 0; ni < 2; ++ni) { accg[mi][ni] = zero4; accu[mi][ni] = zero4; }

    const unsigned char* xbb = (const unsigned char*)xb;

    for (int kt = 0; kt < HH / BK; ++kt) {
        // issue global loads (prefetch before barrier)
        uint4 av[4];
#pragma unroll
        for (int i = 0; i < 4; ++i)
            av[i] = *(const uint4*)(xbb + a_gbl[i] + (size_t)kt * 128);
        vf4 bg4[4], bu4[4];
        const float* wgr = Wg + (size_t)(kt * BK + bk0) * FF + nb + bn0;
        const float* wur = Wu + (size_t)(kt * BK + bk0) * FF + nb + bn0;
#pragma unroll
        for (int j = 0; j < 4; ++j) {
            bg4[j] = *(const vf4*)(wgr + (size_t)j * FF);
            bu4[j] = *(const vf4*)(wur + (size_t)j * FF);
        }
        __syncthreads();   // previous iteration's LDS reads complete
#pragma unroll
        for (int i = 0; i < 4; ++i) *(uint4*)(smem + a_lds[i]) = av[i];
#pragma unroll
        for (int i = 0; i < 4; ++i) {
            uint2 vg, vu;
            vg.x = (uint32)f2bf(bg4[0][i]) | ((uint32)f2bf(bg4[1][i]) << 16);
            vg.y = (uint32)f2bf(bg4[2][i]) | ((uint32)f2bf(bg4[3][i]) << 16);
            vu.x = (uint32)f2bf(bu4[0][i]) | ((uint32)f2bf(bu4[1][i]) << 16);
            vu.y = (uint32)f2bf(bu4[2][i]) | ((uint32)f2bf(bu4[3][i]) << 16);
            *(uint2*)(smem + 16384 + b_lds[i]) = vg;
            *(uint2*)(smem + 24576 + b_lds[i]) = vu;
        }
        __syncthreads();
        // compute: 2 MFMA k-steps of 32
#pragma unroll
        for (int kk = 0; kk < 2; ++kk) {
            const int cb = kk * 64 + ((lane >> 4) << 4);
            bf16x8 af[4], bgf[2], buf_[2];
#pragma unroll
            for (int mi = 0; mi < 4; ++mi) {
                int r = wr * 64 + mi * 16 + (lane & 15);
                af[mi] = *(const bf16x8*)(smem + r * 128 + (cb ^ ((r & 7) << 4)));
            }
#pragma unroll
            for (int ni = 0; ni < 2; ++ni) {
                int n = wc * 32 + ni * 16 + (lane & 15);
                int off = n * 128 + (cb ^ ((n & 7) << 4));
                bgf[ni]  = *(const bf16x8*)(smem + 16384 + off);
                buf_[ni] = *(const bf16x8*)(smem + 24576 + off);
            }
#pragma unroll
            for (int mi = 0; mi < 4; ++mi)
#pragma unroll
                for (int ni = 0; ni < 2; ++ni) {
                    accg[mi][ni] = __builtin_amdgcn_mfma_f32_16x16x32_bf16(af[mi], bgf[ni],  accg[mi][ni], 0, 0, 0);
                    accu[mi][ni] = __builtin_amdgcn_mfma_f32_16x16x32_bf16(af[mi], buf_[ni], accu[mi][ni], 0, 0, 0);
                }
        }
    }

    // epilogue: swiglu + bf16 store into h-buffer
    const int lr = lane >> 4, lc = lane & 15;
#pragma unroll
    for (int mi = 0; mi < 4; ++mi) {
#pragma unroll
        for (int reg = 0; reg < 4; ++reg) {
            int r = wr * 64 + mi * 16 + lr * 4 + reg;
            int gi = m0 + r;
            if (gi < n_e) {
                size_t base = (size_t)(seg0 + gi) * FF;
#pragma unroll
                for (int ni = 0; ni < 2; ++ni) {
                    float g = accg[mi][ni][reg];
                    float u = accu[mi][ni][reg];
                    float hv = g * u / (1.f + __expf(-g));   // silu(g)*u
                    int col = nb + wc * 32 + ni * 16 + lc;
                    hb[base + col] = f2bf(hv);
                }
            }
        }
    }
}

// ---------------- GEMM2: y = h * Wd, scaled by routing weight, scattered to slots ----
__global__ __launch_bounds__(256, 2)
void k_gemm2(const unsigned short* __restrict__ hb, const float* __restrict__ wd,
             const int* __restrict__ offs, const int* __restrict__ row_tok,
             const int* __restrict__ row_slot, const float* __restrict__ row_w,
             float* __restrict__ oacc)
{
    const int e  = blockIdx.y >> 4;
    const int mt = blockIdx.y & 15;
    const int seg0 = offs[e];
    const int n_e  = offs[e + 1] - seg0;
    const int m0 = mt * 128;
    if (m0 >= n_e) return;
    const int nb = blockIdx.x * 64;
    const float* W = wd + (size_t)e * FF * HH;

    __shared__ __align__(16) unsigned char smem[24576];
    // A: [0,16384)   B: [16384,24576)

    const int tid  = threadIdx.x;
    const int lane = tid & 63;
    const int wid  = tid >> 6;
    const int wr = wid >> 1, wc = wid & 1;

    int    a_lds[4];
    size_t a_gbl[4];
#pragma unroll
    for (int i = 0; i < 4; ++i) {
        int flat = tid + i * 256;
        int r  = flat >> 3;
        int cb = (flat & 7) * 16;
        int idx = m0 + r;
        int cidx = idx < n_e ? idx : (n_e - 1);
        a_gbl[i] = (size_t)(seg0 + cidx) * (FF * 2) + (size_t)cb;
        a_lds[i] = r * 128 + (cb ^ ((r & 7) << 4));
    }
    const int gn = tid & 15, gk = tid >> 4;
    const int bn0 = gn * 4, bk0 = gk * 4;
    int b_lds[4];
#pragma unroll
    for (int i = 0; i < 4; ++i) {
        int n = bn0 + i;
        b_lds[i] = n * 128 + ((bk0 * 2) ^ ((n & 7) << 4));
    }

    f32x4v zero4 = {0.f, 0.f, 0.f, 0.f};
    f32x4v acc[4][2];
#pragma unroll
    for (int mi = 0; mi < 4; ++mi)
#pragma unroll
        for (int ni = 0; ni < 2; ++ni) acc[mi][ni] = zero4;

    const unsigned char* hbb = (const unsigned char*)hb;

    for (int kt = 0; kt < FF / BK; ++kt) {
        uint4 av[4];
#pragma unroll
        for (int i = 0; i < 4; ++i)
            av[i] = *(const uint4*)(hbb + a_gbl[i] + (size_t)kt * 128);
        vf4 b4[4];
        const float* wdr = W + (size_t)(kt * BK + bk0) * HH + nb + bn0;
#pragma unroll
        for (int j = 0; j < 4; ++j)
            b4[j] = *(const vf4*)(wdr + (size_t)j * HH);
        __syncthreads();
#pragma unroll
        for (int i = 0; i < 4; ++i) *(uint4*)(smem + a_lds[i]) = av[i];
#pragma unroll
        for (int i = 0; i < 4; ++i) {
            uint2 v;
            v.x = (uint32)f2bf(b4[0][i]) | ((uint32)f2bf(b4[1][i]) << 16);
            v.y = (uint32)f2bf(b4[2][i]) | ((uint32)f2bf(b4[3][i]) << 16);
            *(uint2*)(smem + 16384 + b_lds[i]) = v;
        }
        __syncthreads();
#pragma unroll
        for (int kk = 0; kk < 2; ++kk) {
            const int cb = kk * 64 + ((lane >> 4) << 4);
            bf16x8 af[4], bf_[2];
#pragma unroll
            for (int mi = 0; mi < 4; ++mi) {
                int r = wr * 64 + mi * 16 + (lane & 15);
                af[mi] = *(const bf16x8*)(smem + r * 128 + (cb ^ ((r & 7) << 4)));
            }
#pragma unroll
            for (int ni = 0; ni < 2; ++ni) {
                int n = wc * 32 + ni * 16 + (lane & 15);
                bf_[ni] = *(const bf16x8*)(smem + 16384 + n * 128 + (cb ^ ((n & 7) << 4)));
            }
#pragma unroll
            for (int mi = 0; mi < 4; ++mi)
#pragma unroll
                for (int ni = 0; ni < 2; ++ni)
                    acc[mi][ni] = __builtin_amdgcn_mfma_f32_16x16x32_bf16(af[mi], bf_[ni], acc[mi][ni], 0, 0, 0);
        }
    }

    const int lr = lane >> 4, lc = lane & 15;
#pragma unroll
    for (int mi = 0; mi < 4; ++mi) {
#pragma unroll
        for (int reg = 0; reg < 4; ++reg) {
            int r = wr * 64 + mi * 16 + lr * 4 + reg;
            int gi = m0 + r;
            if (gi < n_e) {
                int ar  = seg0 + gi;
                int tok = row_tok[ar];
                int sl  = row_slot[ar];
                float wgt = row_w[ar];
                size_t base = ((size_t)sl * TT + tok) * HH;
#pragma unroll
                for (int ni = 0; ni < 2; ++ni) {
                    int col = nb + wc * 32 + ni * 16 + lc;
                    oacc[base + col] = wgt * acc[mi][ni][reg];
                }
            }
        }
    }
}

// ---------------- combine: out = fp32(slot0 + slot1)  (d_out is float*!) ----------------
__global__ void k_combine(const float* __restrict__ oacc, float* __restrict__ out)
{
    int i = (blockIdx.x * 256 + threadIdx.x) * 4;
    vf4 a = *(const vf4*)(oacc + i);
    vf4 b = *(const vf4*)(oacc + (size_t)TT * HH + i);
    vf4 s = a + b;
    *(vf4*)(out + i) = s;
}

extern "C" void kernel_launch(void* const* d_in, const int* in_sizes, int n_in,
                              void* d_out, int out_size, void* d_ws, size_t ws_size,
                              hipStream_t stream)
{
    (void)in_sizes; (void)n_in; (void)out_size; (void)ws_size;
    const float* x  = (const float*)d_in[0];
    const float* rw = (const float*)d_in[1];
    const float* wg = (const float*)d_in[2];
    const float* wu = (const float*)d_in[3];
    const float* wd = (const float*)d_in[4];
    float* out = (float*)d_out;   // fp32 output (reference output dtype is float32)

    char* ws = (char*)d_ws;
    size_t off = 0;
    auto alloc = [&](size_t b) { size_t o = off; off += (b + 255) & ~(size_t)255; return o; };
    unsigned short* xb   = (unsigned short*)(ws + alloc((size_t)TT * HH * 2));
    int*   tke      = (int*)  (ws + alloc((size_t)TT * 2 * 4));
    float* tkw      = (float*)(ws + alloc((size_t)TT * 2 * 4));
    int*   counts   = (int*)  (ws + alloc(EE * 4));
    int*   cursor   = (int*)  (ws + alloc(EE * 4));
    int*   offs     = (int*)  (ws + alloc((EE + 1) * 4));
    int*   row_tok  = (int*)  (ws + alloc((size_t)NROWS * 4));
    int*   row_slot = (int*)  (ws + alloc((size_t)NROWS * 4));
    float* row_w    = (float*)(ws + alloc((size_t)NROWS * 4));
    unsigned short* hb = (unsigned short*)(ws + alloc((size_t)NROWS * FF * 2));
    float* oacc     = (float*)(ws + alloc((size_t)2 * TT * HH * 4));

    hipMemsetAsync(counts, 0, EE * 4, stream);
    hipMemsetAsync(cursor, 0, EE * 4, stream);

    k_convert_x<<<(TT * HH) / (256 * 8), 256, 0, stream>>>(x, xb);
    k_router<<<TT / 4, 256, 0, stream>>>(x, rw, tke, tkw, counts);
    k_offsets<<<1, 64, 0, stream>>>(counts, offs);
    k_scatter<<<(TT + 255) / 256, 256, 0, stream>>>(tke, tkw, offs, cursor,
                                                    row_tok, row_slot, row_w);
    dim3 g1(FF / 64, EE * 16);
    k_gemm1<<<g1, 256, 0, stream>>>(xb, wg, wu, offs, row_tok, hb);
    dim3 g2(HH / 64, EE * 16);
    k_gemm2<<<g2, 256, 0, stream>>>(hb, wd, offs, row_tok, row_slot, row_w, oacc);
    k_combine<<<(TT * HH) / (256 * 4), 256, 0, stream>>>(oacc, out);
}